// Round 2
// baseline (319.319 us; speedup 1.0000x reference)
//
#include <hip/hip_runtime.h>
#include <math.h>

// SemiConnectedConv: B=16, C_IN=16, N_BR=32, C_SEL=8, K=5, H=W=224, pad=2.
// Branch i uses channels {c : (c+i)%16 < 8}, sorted ascending; weight j pairs
// with the j-th smallest selected channel:
//   im = i & 15;  c(j) = (im>=9) ? (16-im+j) : ((j <= 7-im) ? j : 8+j)
//
// Block = one (batch, 32x16 spatial tile), computes ALL 32 branches so the
// 16-channel LDS tile is reused 16x per channel. Thread = 8 cols x 4 rows x
// 2 branches (slot, slot+16). Row-register blocking: each 12-float LDS row
// read feeds up to 5 kh taps -> ~0.24 B/FLOP LDS traffic.

#define HH 224
#define WW 224
#define BB 16
#define CIN 16
#define NBR 32
#define TW 32          // tile width  (7 tiles)
#define TH 16          // tile height (14 tiles)
#define LROWS 20       // TH + 4 halo
#define LCOLS 36       // TW + 4 halo
#define LSTRIDE 41     // padded: rg*4*41*4B mod 128 spreads banks; <=2-way free

__global__ __launch_bounds__(256)
void semiconv_kernel(const float* __restrict__ x,
                     const float* __restrict__ Wc,
                     const float* __restrict__ bc,
                     float* __restrict__ out) {
    __shared__ float tile[CIN][LROWS][LSTRIDE];

    const int tx = blockIdx.x;          // 0..6
    const int ty = blockIdx.y;          // 0..13
    const int b  = blockIdx.z;          // 0..15
    const int w0 = tx * TW;
    const int h0 = ty * TH;
    const int tid = threadIdx.x;

    // ---- cooperative load: 16ch x 20rows x 36cols, zero-padded halo ----
    for (int idx = tid; idx < CIN * LROWS * LCOLS; idx += 256) {
        int ch  = idx / (LROWS * LCOLS);
        int rem = idx - ch * (LROWS * LCOLS);
        int row = rem / LCOLS;
        int col = rem - row * LCOLS;
        int gh = h0 - 2 + row;
        int gw = w0 - 2 + col;
        float v = 0.0f;
        if (gh >= 0 && gh < HH && gw >= 0 && gw < WW)
            v = x[((b * CIN + ch) * HH + gh) * WW + gw];
        tile[ch][row][col] = v;
    }
    __syncthreads();

    const int cg   = tid & 3;           // colgroup: cols cg*8 .. cg*8+7
    const int rg   = (tid >> 2) & 3;    // rowgroup: rows rg*4 .. rg*4+3
    const int slot = tid >> 4;          // 0..15 -> branches slot, slot+16

    #pragma unroll
    for (int bsel = 0; bsel < 2; ++bsel) {
        const int bi = slot + 16 * bsel;
        const int im = bi & 15;

        float acc[4][8];
        #pragma unroll
        for (int r = 0; r < 4; ++r)
            #pragma unroll
            for (int o = 0; o < 8; ++o) acc[r][o] = 0.0f;

        const float* wb = Wc + bi * (8 * 25);

        for (int j = 0; j < 8; ++j) {
            // j-th selected channel for this branch
            int c = (im >= 9) ? (16 - im + j) : ((j <= 7 - im) ? j : 8 + j);

            float w[25];
            #pragma unroll
            for (int t = 0; t < 25; ++t) w[t] = wb[j * 25 + t];

            const float* lbase = &tile[c][rg * 4][cg * 8];

            #pragma unroll
            for (int rl = 0; rl < 8; ++rl) {      // local input row
                float rx[12];
                #pragma unroll
                for (int t = 0; t < 12; ++t)
                    rx[t] = lbase[rl * LSTRIDE + t];

                #pragma unroll
                for (int kh = 0; kh < 5; ++kh) {
                    const int orow = rl - kh;      // output row fed by this input row
                    if (orow >= 0 && orow < 4) {
                        #pragma unroll
                        for (int kw = 0; kw < 5; ++kw) {
                            const float wv = w[kh * 5 + kw];
                            #pragma unroll
                            for (int o = 0; o < 8; ++o)
                                acc[orow][o] = fmaf(rx[o + kw], wv, acc[orow][o]);
                        }
                    }
                }
            }
        }

        // ---- epilogue: bias + sigmoid + vectorized store ----
        const float bias = bc[bi];
        #pragma unroll
        for (int r = 0; r < 4; ++r) {
            const int oh = h0 + rg * 4 + r;
            float vals[8];
            #pragma unroll
            for (int o = 0; o < 8; ++o) {
                float s = acc[r][o] + bias;
                vals[o] = 1.0f / (1.0f + __expf(-s));
            }
            float4* op = (float4*)(out +
                (((size_t)(b * NBR + bi) * HH + oh) * WW + w0 + cg * 8));
            op[0] = make_float4(vals[0], vals[1], vals[2], vals[3]);
            op[1] = make_float4(vals[4], vals[5], vals[6], vals[7]);
        }
    }
}

extern "C" void kernel_launch(void* const* d_in, const int* in_sizes, int n_in,
                              void* d_out, int out_size, void* d_ws, size_t ws_size,
                              hipStream_t stream) {
    const float* x  = (const float*)d_in[0];
    const float* Wc = (const float*)d_in[1];
    const float* bc = (const float*)d_in[2];
    float* out = (float*)d_out;

    dim3 grid(WW / TW, HH / TH, BB);   // 7 x 14 x 16
    semiconv_kernel<<<grid, 256, 0, stream>>>(x, Wc, bc, out);
}

// Round 3
// 180.094 us; speedup vs baseline: 1.7731x; 1.7731x over previous
//
#include <hip/hip_runtime.h>
#include <math.h>

// SemiConnectedConv as dense bf16-MFMA implicit GEMM.
// out[pixel, branch] = sum_k patch[pixel,k] * Wd[k,branch], K = 26 taps x 16 ch
// (25 real taps + 1 zero-pad tap; unselected channels get zero weights).
// Block = one (batch, h row): M=224 pixels, N=32 branches, K=416.
// LDS: input slab as bf16 [row 0..5][col 0..227][c 0..15]; row 5 = zeros
// (feeds the pad tap), c-contiguous so an A-fragment is one ds_read_b128.
// mfma_f32_16x16x32_bf16: A lane l -> row m=l&15, k=(l>>4)*8+j;
//                         B lane l -> col n=l&15, k=(l>>4)*8+j;
//                         D lane l -> col n=l&15, row m=(l>>4)*4+reg.
// k decomposes as k = tap_local*16 + c: half = l>>5 picks tap, c0=((l>>4)&1)*8.

#define HH 224
#define WW 224
#define BB 16
#define CIN 16
#define NBR 32
#define KSTEPS 13
#define LROWS 6
#define LCOLS 228

typedef short short8 __attribute__((ext_vector_type(8)));
typedef float f32x4 __attribute__((ext_vector_type(4)));

static __device__ __forceinline__ unsigned short f2bf(float f) {
    unsigned int u = __float_as_uint(f);
    unsigned int r = (u + 0x7FFFu + ((u >> 16) & 1u)) >> 16;   // RNE
    return (unsigned short)r;
}

// ws layout: short bfrag[KSTEPS][2 ntile][64 lane][8]  (26624 bytes)
__global__ __launch_bounds__(64)
void prep_wfrag(const float* __restrict__ Wc, short* __restrict__ ws) {
    int t = blockIdx.x * 64 + threadIdx.x;   // 26 blocks x 64
    int lane = t & 63;
    int rest = t >> 6;            // 0..25
    int nt = rest & 1;
    int kstep = rest >> 1;        // 0..12
    int n = lane & 15;
    int bi = nt * 16 + n;
    int kbase = kstep * 32 + (lane >> 4) * 8;
    short v[8];
    #pragma unroll
    for (int j = 0; j < 8; ++j) {
        int kg = kbase + j;
        float val = 0.0f;
        if (kg < 400) {
            int tap = kg >> 4;        // kh*5+kw
            int c = kg & 15;
            if (((c + bi) & 15) < 8) {             // channel selected
                int jsel = 0;                       // rank among selected
                for (int cc = 0; cc < c; ++cc) jsel += (((cc + bi) & 15) < 8) ? 1 : 0;
                val = Wc[(bi * 8 + jsel) * 25 + tap];
            }
        }
        v[j] = (short)f2bf(val);
    }
    short8 pack;
    #pragma unroll
    for (int j = 0; j < 8; ++j) pack[j] = v[j];
    *(short8*)(ws + (size_t)t * 8) = pack;
}

__global__ __launch_bounds__(448)
void semiconv_mfma(const float* __restrict__ x,
                   const short* __restrict__ wfrag,
                   const float* __restrict__ bc,
                   float* __restrict__ out) {
    __shared__ short tile[LROWS * LCOLS * CIN];   // 43776 B, [row][col][c]

    const int bidx = blockIdx.x;                  // 224 h values, XCD-swizzled
    const int b = blockIdx.y;
    const int h = (bidx & 7) * 28 + (bidx >> 3);  // 8 XCDs x contiguous 28-row band
    const int tid = threadIdx.x;

    // ---- stage: rows 0..4 = x[h-2..h+2] as bf16, row 5 = zeros ----
    for (int idx = tid; idx < LROWS * LCOLS; idx += 448) {
        int row = idx / LCOLS;
        int col = idx - row * LCOLS;
        int gh = h + row - 2;
        int gw = col - 2;
        unsigned int pk[8];
        if (row < 5 && (unsigned)gh < HH && (unsigned)gw < WW) {
            const float* xp = x + ((size_t)b * CIN * HH + gh) * WW + gw;
            #pragma unroll
            for (int cc = 0; cc < 8; ++cc) {
                float f0 = xp[(size_t)(2 * cc    ) * (HH * WW)];
                float f1 = xp[(size_t)(2 * cc + 1) * (HH * WW)];
                pk[cc] = (unsigned)f2bf(f0) | ((unsigned)f2bf(f1) << 16);
            }
        } else {
            #pragma unroll
            for (int cc = 0; cc < 8; ++cc) pk[cc] = 0;
        }
        int4* dst = (int4*)&tile[idx * CIN];      // 32B per item, aligned
        dst[0] = make_int4(pk[0], pk[1], pk[2], pk[3]);
        dst[1] = make_int4(pk[4], pk[5], pk[6], pk[7]);
    }
    __syncthreads();

    // ---- compute: wave = 2 M-tiles x 2 N-tiles, 13 K-steps ----
    const int wave = tid >> 6;                    // 0..6
    const int lane = tid & 63;
    const int m = lane & 15;
    const int c0 = ((lane >> 4) & 1) * 8;
    const int half = lane >> 5;
    const int wbase = wave * 32;
    const int baseIdx = (wbase + m) * CIN + c0;

    f32x4 acc[2][2] = {};
    const short8* wfv = (const short8*)wfrag;

    #pragma unroll
    for (int k = 0; k < KSTEPS; ++k) {
        const int tapA = 2 * k, tapB = 2 * k + 1;
        const int offA = ((tapA / 5) * LCOLS + (tapA % 5)) * CIN;
        const int offB = ((tapB / 5) * LCOLS + (tapB % 5)) * CIN;
        const int tapoff = half ? offB : offA;
        short8 b0 = wfv[(k * 2 + 0) * 64 + lane];
        short8 b1 = wfv[(k * 2 + 1) * 64 + lane];
        #pragma unroll
        for (int mt = 0; mt < 2; ++mt) {
            short8 a = *(const short8*)&tile[tapoff + baseIdx + mt * 16 * CIN];
            acc[mt][0] = __builtin_amdgcn_mfma_f32_16x16x32_bf16(a, b0, acc[mt][0], 0, 0, 0);
            acc[mt][1] = __builtin_amdgcn_mfma_f32_16x16x32_bf16(a, b1, acc[mt][1], 0, 0, 0);
        }
    }

    // ---- epilogue: bias + sigmoid, scalar stores (64B/branch coalesced) ----
    const int rowm = (lane >> 4) * 4;
    #pragma unroll
    for (int nt = 0; nt < 2; ++nt) {
        const int branch = nt * 16 + m;           // D col = lane&15
        const float bias = bc[branch];
        #pragma unroll
        for (int mt = 0; mt < 2; ++mt) {
            #pragma unroll
            for (int r = 0; r < 4; ++r) {
                const int w = wbase + mt * 16 + rowm + r;
                float s = acc[mt][nt][r] + bias;
                float sg = 1.0f / (1.0f + __expf(-s));
                out[(((size_t)b * NBR + branch) * HH + h) * WW + w] = sg;
            }
        }
    }
}

extern "C" void kernel_launch(void* const* d_in, const int* in_sizes, int n_in,
                              void* d_out, int out_size, void* d_ws, size_t ws_size,
                              hipStream_t stream) {
    const float* x  = (const float*)d_in[0];
    const float* Wc = (const float*)d_in[1];
    const float* bc = (const float*)d_in[2];
    float* out = (float*)d_out;
    short* wfrag = (short*)d_ws;                  // 26624 B used

    prep_wfrag<<<26, 64, 0, stream>>>(Wc, wfrag);
    dim3 grid(224, 16);                           // (h, b)
    semiconv_mfma<<<grid, 448, 0, stream>>>(x, wfrag, bc, out);
}